// Round 6
// baseline (524.079 us; speedup 1.0000x reference)
//
#include <hip/hip_runtime.h>
#include <hip/hip_bf16.h>
#include <stdint.h>

#define N_NODES   65536
#define N_GRAPHS  1024
#define N_EDGES   1048576
#define IN_FEATS  512
#define HIDDEN    1024
#define H4        256
#define EMB_DIM   512
#define RDIM      1792   // 512 + 1024 + 256
#define EPS_F     1e-5f
#define SLOPE_F   0.01f

typedef __bf16 bf16;
typedef __bf16 bf16x8 __attribute__((ext_vector_type(8)));
typedef float  floatx4 __attribute__((ext_vector_type(4)));

#define GLDS16(gp, lp) __builtin_amdgcn_global_load_lds( \
    (const __attribute__((address_space(1))) void*)(gp), \
    (__attribute__((address_space(3))) void*)(lp), 16, 0, 0)

#define MFMA16(a, b, c) __builtin_amdgcn_mfma_f32_16x16x32_bf16((a), (b), (c), 0, 0, 0)

// -------------------------------------------- fused edge pass, per graph
__global__ __launch_bounds__(256) void k_graph_build(
    const int* __restrict__ src, const int* __restrict__ dst,
    const float* __restrict__ ew,
    bf16* __restrict__ adjb, float* __restrict__ scl_o)
{
    __shared__ float sAdj[4096];
    __shared__ float sDegO[64], sDegI[64];
    int g = blockIdx.x, tid = threadIdx.x;
    for (int i = tid; i < 4096; i += 256) sAdj[i] = 0.f;
    if (tid < 64) { sDegO[tid] = 0.f; sDegI[tid] = 0.f; }
    __syncthreads();
    int e0 = g * 1024;
    #pragma unroll
    for (int i = 0; i < 4; ++i) {
        int e = e0 + i * 256 + tid;
        int s = src[e] & 63, d = dst[e] & 63;
        atomicAdd(&sAdj[(d << 6) | s], ew[e]);
        atomicAdd(&sDegO[s], 1.f);
        atomicAdd(&sDegI[d], 1.f);
    }
    __syncthreads();
    if (tid < 64) scl_o[g * 64 + tid] = rsqrtf(fmaxf(sDegO[tid], 1.f));
    bf16* ag = adjb + ((size_t)g << 12);
    for (int i = tid; i < 4096; i += 256) {
        float si = rsqrtf(fmaxf(sDegI[i >> 6], 1.f));
        ag[i] = (bf16)(sAdj[i] * si);
    }
}

// ---------------------------- LDS-tiled weight transpose (coalesced writes)
__global__ __launch_bounds__(256) void k_transpose_tiled(
    const float* __restrict__ W1, const float* __restrict__ W2,
    const float* __restrict__ Wemb,
    bf16* __restrict__ W1T, bf16* __restrict__ W2T, bf16* __restrict__ WembT)
{
    int b = blockIdx.x, tid = threadIdx.x;
    const float* W; bf16* WT; int K, N, kt, nt;
    if (b < 512)      { W = W1;   WT = W1T;   K = 512;  N = 1024; kt = b >> 5;  nt = b & 31; }
    else if (b < 768) { int i = b - 512; W = W2;   WT = W2T;   K = 1024; N = 256;  kt = i >> 3;  nt = i & 7; }
    else              { int i = b - 768; W = Wemb; WT = WembT; K = 1792; N = 512;  kt = i >> 4;  nt = i & 15; }
    __shared__ float t[32][33];
    int c = tid & 31, r8 = tid >> 5;
    #pragma unroll
    for (int rr = 0; rr < 32; rr += 8)
        t[rr + r8][c] = W[(size_t)(kt * 32 + rr + r8) * N + nt * 32 + c];
    __syncthreads();
    #pragma unroll
    for (int rr = 0; rr < 32; rr += 8)
        WT[(size_t)(nt * 32 + rr + r8) * K + kt * 32 + c] = (bf16)t[c][rr + r8];
}

// -------------------------------------- fused prep + agg layer 1 (2 blk/graph)
__global__ __launch_bounds__(256) void k_prep_agg1(
    const float* __restrict__ x, const float* __restrict__ so,
    const bf16* __restrict__ adjb,
    bf16* __restrict__ axs1, bf16* __restrict__ Rb)
{
    __shared__ __align__(16) bf16 sOut[64 * 264];
    __shared__ float sSo[64];
    int g = blockIdx.x >> 1, half = blockIdx.x & 1;
    int tid = threadIdx.x, lane = tid & 63, wave = tid >> 6, q = lane >> 4;
    if (tid < 64) sSo[tid] = so[g * 64 + tid];
    const float* xg = x + (size_t)g * 64 * IN_FEATS + half * 256;
    const bf16* ag = adjb + ((size_t)g << 12);

    bf16x8 af[4][2];
    #pragma unroll
    for (int mt = 0; mt < 4; ++mt)
        #pragma unroll
        for (int kk = 0; kk < 2; ++kk)
            af[mt][kk] = *(const bf16x8*)&ag[(mt * 16 + (lane & 15)) * 64 + kk * 32 + q * 8];
    __syncthreads();
    float sov[2][8];
    #pragma unroll
    for (int kk = 0; kk < 2; ++kk)
        #pragma unroll
        for (int j = 0; j < 8; ++j) sov[kk][j] = sSo[kk * 32 + q * 8 + j];

    #pragma unroll
    for (int nt = 0; nt < 4; ++nt) {
        int cl = wave * 64 + nt * 16 + (lane & 15);
        floatx4 acc[4] = {};
        float r0 = 0.f;
        #pragma unroll
        for (int kk = 0; kk < 2; ++kk) {
            bf16x8 bfrag;
            #pragma unroll
            for (int j = 0; j < 8; ++j) {
                float v = xg[(size_t)(kk * 32 + q * 8 + j) * IN_FEATS + cl];
                r0 += v;
                bfrag[j] = (bf16)(v * sov[kk][j]);
            }
            #pragma unroll
            for (int mt = 0; mt < 4; ++mt)
                acc[mt] = MFMA16(af[mt][kk], bfrag, acc[mt]);
        }
        r0 += __shfl_xor(r0, 16);
        r0 += __shfl_xor(r0, 32);
        if (lane < 16) Rb[(size_t)g * RDIM + half * 256 + cl] = (bf16)(r0 * (1.f / 64.f));
        #pragma unroll
        for (int mt = 0; mt < 4; ++mt)
            #pragma unroll
            for (int i = 0; i < 4; ++i)
                sOut[(mt * 16 + q * 4 + i) * 264 + cl] = (bf16)acc[mt][i];
    }
    __syncthreads();
    #pragma unroll
    for (int it = 0; it < 8; ++it) {
        int idx = it * 256 + tid;
        int d = idx >> 5, c8 = idx & 31;
        *(bf16x8*)&axs1[(size_t)(g * 64 + d) * IN_FEATS + half * 256 + c8 * 8] =
            *(const bf16x8*)&sOut[d * 264 + c8 * 8];
    }
}

// ------------------- K-loop: A staged via dbuf global_load_lds, B direct from
// global (L2-resident weights). One barrier per iter; drain overlaps compute.
template<int ROWS>   // rows in A tile: 128 or 64
__device__ __forceinline__ void kloop_bdirect(
    const bf16* __restrict__ Abase,   // A + row0*K
    const bf16* __restrict__ bp,      // BT + (colbase+l15)*K + q*8  (per-lane)
    int K, int k0_start, int niter,
    bf16* __restrict__ sbuf0, bf16* __restrict__ sbuf1,
    int rbase, int tid, int wave, int q, int l15,
    floatx4 (&acc)[4][4])
{
    constexpr int UPT = ROWS * 8 / 256;   // 16B units per thread
    #pragma unroll
    for (int i = 0; i < UPT; ++i) {       // prologue stage -> sbuf0
        int u = i * 256 + tid;
        int r = u >> 3, c = (u & 7) ^ (r & 7);
        GLDS16(Abase + (size_t)r * K + (k0_start + c * 8), &sbuf0[(i * 256 + wave * 64) * 8]);
    }
    for (int it = 0; it < niter; ++it) {
        int k0 = k0_start + it * 64;
        bf16* cur = (it & 1) ? sbuf1 : sbuf0;
        bf16* nxt = (it & 1) ? sbuf0 : sbuf1;
        asm volatile("s_waitcnt vmcnt(0)" ::: "memory");
        __syncthreads();
        if (it + 1 < niter) {
            #pragma unroll
            for (int i = 0; i < UPT; ++i) {
                int u = i * 256 + tid;
                int r = u >> 3, c = (u & 7) ^ (r & 7);
                GLDS16(Abase + (size_t)r * K + (k0 + 64 + c * 8), &nxt[(i * 256 + wave * 64) * 8]);
            }
        }
        const bf16* bpk = bp + k0;
        bf16x8 b0[4], b1[4], afr[4];
        #pragma unroll
        for (int nt = 0; nt < 4; ++nt) b0[nt] = *(const bf16x8*)(bpk + (size_t)nt * 16 * K);
        #pragma unroll
        for (int nt = 0; nt < 4; ++nt) b1[nt] = *(const bf16x8*)(bpk + (size_t)nt * 16 * K + 32);
        #pragma unroll
        for (int mt = 0; mt < 4; ++mt) {
            int r = rbase + mt * 16 + l15;
            afr[mt] = *(const bf16x8*)&cur[(r * 8 + (q ^ (r & 7))) * 8];
        }
        #pragma unroll
        for (int mt = 0; mt < 4; ++mt)
            #pragma unroll
            for (int nt = 0; nt < 4; ++nt)
                acc[mt][nt] = MFMA16(afr[mt], b0[nt], acc[mt][nt]);
        #pragma unroll
        for (int mt = 0; mt < 4; ++mt) {
            int r = rbase + mt * 16 + l15;
            afr[mt] = *(const bf16x8*)&cur[(r * 8 + ((4 + q) ^ (r & 7))) * 8];
        }
        #pragma unroll
        for (int mt = 0; mt < 4; ++mt)
            #pragma unroll
            for (int nt = 0; nt < 4; ++nt)
                acc[mt][nt] = MFMA16(afr[mt], b1[nt], acc[mt][nt]);
    }
}

__device__ __forceinline__ void swizzle_block(int cb, int& bx, int& by)
{
    int b = blockIdx.y * gridDim.x + blockIdx.x;
    int xcd = b & 7, t = b >> 3;
    bx = t % cb;
    by = (t / cb) * 8 + xcd;
}

// ---------------- GEMM1: axs1@W1 + GraphNorm + leaky + r1 + xs2(scaled) store
__global__ __launch_bounds__(256) void k_gemm1_f(
    const bf16* __restrict__ A, const bf16* __restrict__ BT,
    const float* __restrict__ alpha, const float* __restrict__ gamma,
    const float* __restrict__ beta,
    const float* __restrict__ so,
    bf16* __restrict__ xs2, bf16* __restrict__ Rb)
{
    __shared__ __align__(16) bf16 sm[128 * 136];   // 34816 B; dbuf uses 2x8192 el
    __shared__ float sSo[128];
    const int tid = threadIdx.x;
    const int lane = tid & 63, wave = tid >> 6, q = lane >> 4, l15 = lane & 15;
    const int wm = wave & 1, wn = wave >> 1;
    int bx, by; swizzle_block(gridDim.x, bx, by);
    const int row0 = by * 128, col0 = bx * 128;

    if (tid < 128) sSo[tid] = so[row0 + tid];

    floatx4 acc[4][4] = {};
    kloop_bdirect<128>(A + (size_t)row0 * IN_FEATS,
                       BT + (size_t)(col0 + wn * 64 + l15) * IN_FEATS + q * 8,
                       IN_FEATS, 0, 8, sm, sm + 8192,
                       wm * 64, tid, wave, q, l15, acc);
    __syncthreads();   // before reusing sm as sOut

    const int gw = by * 2 + wm;
    bf16* sOut = sm;                                // [128 r][136 pitch]
    #pragma unroll
    for (int nt = 0; nt < 4; ++nt) {
        int cl = wn * 64 + nt * 16 + l15;
        int colg = col0 + cl;
        float lsum = 0.f;
        #pragma unroll
        for (int mt = 0; mt < 4; ++mt)
            #pragma unroll
            for (int i = 0; i < 4; ++i) lsum += acc[mt][nt][i];
        lsum += __shfl_xor(lsum, 16);
        lsum += __shfl_xor(lsum, 32);
        float am = alpha[colg] * (lsum * (1.f / 64.f));
        float gm = gamma[colg], bt = beta[colg];
        float sub[4][4], qv = 0.f;
        #pragma unroll
        for (int mt = 0; mt < 4; ++mt)
            #pragma unroll
            for (int i = 0; i < 4; ++i) {
                float d = acc[mt][nt][i] - am;
                sub[mt][i] = d; qv += d * d;
            }
        qv += __shfl_xor(qv, 16);
        qv += __shfl_xor(qv, 32);
        float rs = rsqrtf(qv * (1.f / 64.f) + EPS_F);
        float rsum = 0.f;
        #pragma unroll
        for (int mt = 0; mt < 4; ++mt)
            #pragma unroll
            for (int i = 0; i < 4; ++i) {
                float o = gm * sub[mt][i] * rs + bt;
                o = (o >= 0.f) ? o : SLOPE_F * o;
                rsum += o;
                int r = wm * 64 + mt * 16 + q * 4 + i;
                sOut[r * 136 + cl] = (bf16)(o * sSo[r]);
            }
        rsum += __shfl_xor(rsum, 16);
        rsum += __shfl_xor(rsum, 32);
        if (lane < 16)
            Rb[(size_t)gw * RDIM + 512 + colg] = (bf16)(rsum * (1.f / 64.f));
    }
    __syncthreads();
    #pragma unroll
    for (int it = 0; it < 8; ++it) {
        int idx = it * 256 + tid;
        int r = idx >> 4, c8 = idx & 15;
        *(bf16x8*)&xs2[(size_t)(row0 + r) * HIDDEN + col0 + c8 * 8] =
            *(const bf16x8*)&sOut[r * 136 + c8 * 8];
    }
}

// ---- GEMM2: one graph per block (BM=64, BN=256=all of H4), K=1024.
__global__ __launch_bounds__(256) void k_gemm2_f(
    const bf16* __restrict__ A, const bf16* __restrict__ BT,
    const bf16* __restrict__ adjb,
    const float* __restrict__ alpha, const float* __restrict__ gamma,
    const float* __restrict__ beta,
    bf16* __restrict__ Rb)
{
    __shared__ __align__(16) bf16 sm[128 * 136];   // dbuf 2x4096 el; sT reuse
    const int g = blockIdx.x, tid = threadIdx.x;
    const int lane = tid & 63, wave = tid >> 6, q = lane >> 4, l15 = lane & 15;

    floatx4 acc[4][4] = {};
    kloop_bdirect<64>(A + ((size_t)g << 6) * HIDDEN,
                      BT + (size_t)(wave * 64 + l15) * HIDDEN + q * 8,
                      HIDDEN, 0, 16, sm, sm + 4096,
                      0, tid, wave, q, l15, acc);
    __syncthreads();   // before reusing sm as sT

    // transpose wave's 64x64 quadrant into LDS [col][node pitch 68]
    bf16* sT = sm + wave * (64 * 68);
    #pragma unroll
    for (int nt = 0; nt < 4; ++nt) {
        int cl = nt * 16 + l15;
        #pragma unroll
        for (int mt = 0; mt < 4; ++mt)
            #pragma unroll
            for (int i = 0; i < 4; ++i)
                sT[cl * 68 + mt * 16 + q * 4 + i] = (bf16)acc[mt][nt][i];
    }
    asm volatile("s_waitcnt lgkmcnt(0)" ::: "memory");   // wave-local LDS RAW

    const bf16* ag = adjb + ((size_t)g << 12);
    floatx4 a2[4][4] = {};
    #pragma unroll
    for (int kk = 0; kk < 2; ++kk) {
        bf16x8 afr[4], bfr[4];
        #pragma unroll
        for (int mt = 0; mt < 4; ++mt)
            afr[mt] = *(const bf16x8*)&ag[(mt * 16 + l15) * 64 + kk * 32 + q * 8];
        #pragma unroll
        for (int nt = 0; nt < 4; ++nt)
            bfr[nt] = *(const bf16x8*)&sT[(nt * 16 + l15) * 68 + kk * 32 + q * 8];
        #pragma unroll
        for (int mt = 0; mt < 4; ++mt)
            #pragma unroll
            for (int nt = 0; nt < 4; ++nt)
                a2[mt][nt] = MFMA16(afr[mt], bfr[nt], a2[mt][nt]);
    }

    #pragma unroll
    for (int nt = 0; nt < 4; ++nt) {
        int colg = wave * 64 + nt * 16 + l15;            // 0..255
        float lsum = 0.f;
        #pragma unroll
        for (int mt = 0; mt < 4; ++mt)
            #pragma unroll
            for (int i = 0; i < 4; ++i) lsum += a2[mt][nt][i];
        lsum += __shfl_xor(lsum, 16);
        lsum += __shfl_xor(lsum, 32);
        float am = alpha[colg] * (lsum * (1.f / 64.f));
        float gm = gamma[colg], bt = beta[colg];
        float sub[4][4], qv = 0.f;
        #pragma unroll
        for (int mt = 0; mt < 4; ++mt)
            #pragma unroll
            for (int i = 0; i < 4; ++i) {
                float d = a2[mt][nt][i] - am;
                sub[mt][i] = d; qv += d * d;
            }
        qv += __shfl_xor(qv, 16);
        qv += __shfl_xor(qv, 32);
        float rs = rsqrtf(qv * (1.f / 64.f) + EPS_F);
        float rsum = 0.f;
        #pragma unroll
        for (int mt = 0; mt < 4; ++mt)
            #pragma unroll
            for (int i = 0; i < 4; ++i) {
                float o = gm * sub[mt][i] * rs + bt;
                rsum += (o >= 0.f) ? o : SLOPE_F * o;
            }
        rsum += __shfl_xor(rsum, 16);
        rsum += __shfl_xor(rsum, 32);
        if (lane < 16)
            Rb[(size_t)g * RDIM + 1536 + colg] = (bf16)(rsum * (1.f / 64.f));
    }
}

// --------------------------- readout GEMM, split-K=4, fp32 partials to embP
__global__ __launch_bounds__(256) void k_gemm_ro(
    const bf16* __restrict__ A, const bf16* __restrict__ BT,
    float* __restrict__ embP)
{
    __shared__ __align__(16) bf16 sm[16384];
    const int tid = threadIdx.x;
    const int lane = tid & 63, wave = tid >> 6, q = lane >> 4, l15 = lane & 15;
    const int wm = wave & 1, wn = wave >> 1;
    const int row0 = blockIdx.y * 128, col0 = blockIdx.x * 128;
    const int kz = blockIdx.z;                 // 4 slices of 448

    floatx4 acc[4][4] = {};
    kloop_bdirect<128>(A + (size_t)row0 * RDIM,
                       BT + (size_t)(col0 + wn * 64 + l15) * RDIM + q * 8,
                       RDIM, kz * 448, 7, sm, sm + 8192,
                       wm * 64, tid, wave, q, l15, acc);

    float* Cout = embP + (size_t)kz * (N_GRAPHS * EMB_DIM);
    #pragma unroll
    for (int mt = 0; mt < 4; ++mt)
        #pragma unroll
        for (int nt = 0; nt < 4; ++nt) {
            int col = col0 + wn * 64 + nt * 16 + l15;
            #pragma unroll
            for (int i = 0; i < 4; ++i) {
                int row = row0 + wm * 64 + mt * 16 + q * 4 + i;
                Cout[(size_t)row * EMB_DIM + col] = acc[mt][nt][i];
            }
        }
}

// ------------------------------- InstanceNorm + leaky (sums split-K partials)
__global__ __launch_bounds__(256) void k_instnorm(
    const float* __restrict__ embP, float* __restrict__ out)
{
    const int P = N_GRAPHS * EMB_DIM;
    int row = blockIdx.x, tid = threadIdx.x;
    int lane = tid & 63, wave = tid >> 6;
    __shared__ float sS[4], sQ[4];
    size_t b = (size_t)row * EMB_DIM + tid;
    float v0 = embP[b] + embP[b + P] + embP[b + 2 * P] + embP[b + 3 * P];
    float v1 = embP[b + 256] + embP[b + 256 + P] + embP[b + 256 + 2 * P] + embP[b + 256 + 3 * P];
    float s = v0 + v1, q = v0 * v0 + v1 * v1;
    #pragma unroll
    for (int off = 32; off; off >>= 1) {
        s += __shfl_down(s, off);
        q += __shfl_down(q, off);
    }
    if (lane == 0) { sS[wave] = s; sQ[wave] = q; }
    __syncthreads();
    float S = sS[0] + sS[1] + sS[2] + sS[3];
    float Q = sQ[0] + sQ[1] + sQ[2] + sQ[3];
    float mu = S * (1.f / 512.f);
    float var = Q * (1.f / 512.f) - mu * mu;
    float rs = rsqrtf(var + EPS_F);
    float o0 = (v0 - mu) * rs; o0 = (o0 >= 0.f) ? o0 : SLOPE_F * o0;
    float o1 = (v1 - mu) * rs; o1 = (o1 >= 0.f) ? o1 : SLOPE_F * o1;
    out[(size_t)row * EMB_DIM + tid]       = o0;
    out[(size_t)row * EMB_DIM + 256 + tid] = o1;
}

// ----------------------------------------------------------------- launcher
extern "C" void kernel_launch(void* const* d_in, const int* in_sizes, int n_in,
                              void* d_out, int out_size, void* d_ws, size_t ws_size,
                              hipStream_t stream) {
    const float* x    = (const float*)d_in[0];
    const float* ew   = (const float*)d_in[1];
    const float* W1   = (const float*)d_in[2];
    const float* W2   = (const float*)d_in[3];
    const float* Wemb = (const float*)d_in[4];
    const float* a1   = (const float*)d_in[5];
    const float* g1   = (const float*)d_in[6];
    const float* b1   = (const float*)d_in[7];
    const float* a2   = (const float*)d_in[8];
    const float* g2   = (const float*)d_in[9];
    const float* b2   = (const float*)d_in[10];
    const int* esrc   = (const int*)d_in[11];
    const int* edst   = (const int*)d_in[12];
    float* out = (float*)d_out;

    char* ws = (char*)d_ws;
    const size_t MB = 1024ull * 1024ull;
    bf16*  adjb   = (bf16*)(ws);                       // 8 MB
    float* scl_o  = (float*)(ws + 8 * MB);             // 256 KB
    bf16*  Rb     = (bf16*)(ws + 9 * MB);              // 3.5 MB
    bf16*  W1T    = (bf16*)(ws + 13 * MB);             // 1 MB
    bf16*  W2T    = (bf16*)(ws + 14 * MB);             // 0.5 MB
    bf16*  WembT  = (bf16*)(ws + 15 * MB);             // 1.75 MB
    float* embP   = (float*)(ws + 17 * MB);            // 8 MB (4 partials)
    bf16*  axs1   = (bf16*)(ws + 25 * MB);             // 64 MB
    bf16*  xs2    = (bf16*)(ws + 89 * MB);             // 128 MB (ends 217M)

    k_graph_build<<<N_GRAPHS, 256, 0, stream>>>(esrc, edst, ew, adjb, scl_o);
    k_transpose_tiled<<<1664, 256, 0, stream>>>(W1, W2, Wemb, W1T, W2T, WembT);

    k_prep_agg1<<<N_GRAPHS * 2, 256, 0, stream>>>(x, scl_o, adjb, axs1, Rb);

    k_gemm1_f<<<dim3(HIDDEN / 128, N_NODES / 128), 256, 0, stream>>>(
        axs1, W1T, a1, g1, b1, scl_o, xs2, Rb);
    k_gemm2_f<<<N_GRAPHS, 256, 0, stream>>>(
        xs2, W2T, adjb, a2, g2, b2, Rb);
    k_gemm_ro<<<dim3(EMB_DIM / 128, N_GRAPHS / 128, 4), 256, 0, stream>>>(
        Rb, WembT, embP);
    k_instnorm<<<N_GRAPHS, 256, 0, stream>>>(embP, out);

    (void)in_sizes; (void)n_in; (void)out_size; (void)ws_size;
}